// Round 5
// baseline (432.113 us; speedup 1.0000x reference)
//
#include <hip/hip_runtime.h>
#include <stdint.h>

typedef unsigned short u16;
typedef __attribute__((ext_vector_type(8))) short short8;
typedef __attribute__((ext_vector_type(4))) float f32x4;
typedef __attribute__((ext_vector_type(4))) uint32_t u32x4;

#define B_   2
#define NQ_  2048
#define NKV_ 2048
#define D_   2048
#define H_   16
#define HD_  128
#define MM_  (B_*NQ_)   // 4096
#define LOG2E 1.4426950408889634f
#define QSCALE (0.08838834764831845f * 1.4426950408889634f)

__device__ __forceinline__ u16 f2bf(float f) {
  uint32_t u = __float_as_uint(f);
  u += 0x7fffu + ((u >> 16) & 1u);
  return (u16)(u >> 16);
}

__device__ __forceinline__ uint32_t cvtpk(float lo, float hi) {
  uint32_t r;
  asm("v_cvt_pk_bf16_f32 %0, %1, %2" : "=v"(r) : "v"(lo), "v"(hi));
  return r;
}

__device__ __forceinline__ void gload_lds16(const void* g, void* l) {
  __builtin_amdgcn_global_load_lds(
      (const __attribute__((address_space(1))) void*)g,
      (__attribute__((address_space(3))) void*)l, 16, 0, 0);
}

// ---------------------------------------------------------------- fused casts
__global__ __launch_bounds__(256) void cast_all(
    const float* __restrict__ x,  const float* __restrict__ qw,
    const float* __restrict__ ow, const float* __restrict__ k,
    const float* __restrict__ v,
    u16* __restrict__ xo, u16* __restrict__ qwo, u16* __restrict__ owo,
    u16* __restrict__ ko, u16* __restrict__ vo)
{
  int i = blockIdx.x * 256 + threadIdx.x;   // units of 8 floats
  const float* s; u16* d; int off;
  if      (i < 1048576) { s = x;  d = xo;  off = i; }
  else if (i < 1572864) { s = qw; d = qwo; off = i - 1048576; }
  else if (i < 2097152) { s = ow; d = owo; off = i - 1572864; }
  else if (i < 3145728) { s = k;  d = ko;  off = i - 2097152; }
  else                  { s = v;  d = vo;  off = i - 3145728; }
  const float4* sp = (const float4*)s + (size_t)off * 2;
  float4 a = sp[0], b = sp[1];
  short8 o;
  o[0] = (short)f2bf(a.x); o[1] = (short)f2bf(a.y);
  o[2] = (short)f2bf(a.z); o[3] = (short)f2bf(a.w);
  o[4] = (short)f2bf(b.x); o[5] = (short)f2bf(b.y);
  o[6] = (short)f2bf(b.z); o[7] = (short)f2bf(b.w);
  *((short8*)d + off) = o;
}

__global__ __launch_bounds__(256) void build_bias(const int* __restrict__ labels,
                                                  const unsigned char* __restrict__ mask,
                                                  const float* __restrict__ tb,
                                                  float* __restrict__ out, int n) {
  int i = blockIdx.x * 256 + threadIdx.x;
  if (i < n) out[i] = mask[i] ? -1e30f : tb[labels[i]] * LOG2E;
}

// ---------------------------------------------------------------- GEMM 256x256 (m201 geometry)
// C[4096][2048] = (A @ W^T + bias) * escale. 256^2 tile, BK=64, 512 thr
// (8 waves 2M x 4N, wave out 128x64). LDS 2x(32+32)KB = 128KB dbuf.
// Per K-tile: stage(t+1) 8 glds/thread -> vmcnt(8) -> barrier -> 24 ds_read_b128
// + 64 MFMA -> barrier. vmcnt never 0 mid-loop (T4). XOR chunk swizzle both sides.
template<int OUT_BF16>
__global__ __launch_bounds__(512, 2) void gemm256(
    const u16* __restrict__ A, const u16* __restrict__ W,
    const float* __restrict__ bias, void* __restrict__ Cout, float escale)
{
  __shared__ u16 As[2][256 * 64];   // 64 KB
  __shared__ u16 Bs[2][256 * 64];   // 64 KB
  const int tid = threadIdx.x;
  const int w = tid >> 6, l = tid & 63;
  const int lr = l & 15, lg = l >> 4;
  const int wm = w >> 2, wn = w & 3;
  int bid = blockIdx.x;                       // 128 blocks = 16 Mt x 8 Nt
  int swz = (bid & 7) * 16 + (bid >> 3);      // bijective (128 % 8 == 0)
  const int bm = swz >> 3, bn = swz & 7;

  f32x4 acc[8][4] = {};   // 128 VGPR

  const int srow = tid >> 3;   // [0,64)
  const int sch  = tid & 7;

  auto stage = [&](int buf, int kt) {
#pragma unroll
    for (int i = 0; i < 4; ++i) {
      int r = srow + i * 64;
      int gc = kt + ((sch ^ (r & 7)) << 3);   // pre-swizzled source chunk
      gload_lds16(A + (size_t)(bm * 256 + r) * 2048 + gc,
                  (char*)&As[buf][0] + tid * 16 + i * 8192);
      gload_lds16(W + (size_t)(bn * 256 + r) * 2048 + gc,
                  (char*)&Bs[buf][0] + tid * 16 + i * 8192);
    }
  };

  stage(0, 0);
  int cur = 0;
  for (int t = 0; t < 32; ++t) {
    if (t < 31) {
      stage(cur ^ 1, (t + 1) * 64);                      // prefetch next tile
      asm volatile("s_waitcnt vmcnt(8)" ::: "memory");   // tile t landed; t+1 in flight
    } else {
      asm volatile("s_waitcnt vmcnt(0)" ::: "memory");
    }
    __builtin_amdgcn_s_barrier();
    __builtin_amdgcn_sched_barrier(0);

    const char* pa = (const char*)&As[cur][0];
    const char* pb = (const char*)&Bs[cur][0];
    short8 bv[4][2];
#pragma unroll
    for (int nf = 0; nf < 4; ++nf) {
      int row = wn * 64 + nf * 16 + lr;
#pragma unroll
      for (int ks = 0; ks < 2; ++ks) {
        int ch = (ks * 4 + lg) ^ (row & 7);
        bv[nf][ks] = *(const short8*)(pb + row * 128 + ch * 16);
      }
    }
#pragma unroll
    for (int mh = 0; mh < 2; ++mh) {
      short8 av[4][2];
#pragma unroll
      for (int mf = 0; mf < 4; ++mf) {
        int row = wm * 128 + mh * 64 + mf * 16 + lr;
#pragma unroll
        for (int ks = 0; ks < 2; ++ks) {
          int ch = (ks * 4 + lg) ^ (row & 7);
          av[mf][ks] = *(const short8*)(pa + row * 128 + ch * 16);
        }
      }
      __builtin_amdgcn_s_setprio(1);
#pragma unroll
      for (int mf = 0; mf < 4; ++mf)
#pragma unroll
        for (int nf = 0; nf < 4; ++nf)
#pragma unroll
          for (int ks = 0; ks < 2; ++ks)
            acc[mh * 4 + mf][nf] = __builtin_amdgcn_mfma_f32_16x16x32_bf16(
                av[mf][ks], bv[nf][ks], acc[mh * 4 + mf][nf], 0, 0, 0);
      __builtin_amdgcn_s_setprio(0);
    }
    __builtin_amdgcn_s_barrier();   // all reads of buf done before next stage
    cur ^= 1;
  }

  // epilogue
#pragma unroll
  for (int nf = 0; nf < 4; ++nf) {
    int col = bn * 256 + wn * 64 + nf * 16 + lr;
    float bb = bias[col];
#pragma unroll
    for (int mfg = 0; mfg < 8; ++mfg) {
#pragma unroll
      for (int r = 0; r < 4; ++r) {
        size_t row = (size_t)(bm * 256 + wm * 128 + mfg * 16 + lg * 4 + r);
        float vv = (acc[mfg][nf][r] + bb) * escale;
        if (OUT_BF16) ((u16*)Cout)[row * 2048 + col] = f2bf(vv);
        else          ((float*)Cout)[row * 2048 + col] = vv;
      }
    }
  }
}

// ---------------------------------------------------------------- attention
// 8 waves / 512 thr: waves 0-3 = long stream (qtB), waves 4-7 = short (qtA).
// Each wave: one 16-q-row strip, swapped QK^T, in-reg softmax (defer-max),
// P->A-frag via shfl. 2 blocks/CU -> 4 waves/SIMD.
__device__ __forceinline__ void softmax16(
    const f32x4 s[4], const f32x4 bias4[4], bool diag, int qrow, int kv0,
    int lr, int lg, float& m, float& d, f32x4 o[8], short8 ap[2])
{
  float sv[4][4];
  float pm = -3e38f;
#pragma unroll
  for (int nf = 0; nf < 4; ++nf)
#pragma unroll
    for (int r = 0; r < 4; ++r) {
      float v = s[nf][r] + bias4[nf][r];
      if (diag) {
        int kv = kv0 + nf * 16 + lg * 4 + r;
        if (kv > qrow) v = -1e30f;
      }
      sv[nf][r] = v;
      pm = fmaxf(pm, v);
    }
  pm = fmaxf(pm, __shfl_xor(pm, 16));
  pm = fmaxf(pm, __shfl_xor(pm, 32));
  if (__any(pm > m + 8.f)) {
    float mn = fmaxf(m, pm);
    float al = __builtin_exp2f(m - mn);
    m = mn;
    d *= al;
    float alr[4];
#pragma unroll
    for (int r = 0; r < 4; ++r) alr[r] = __shfl(al, lg * 4 + r);
#pragma unroll
    for (int nf = 0; nf < 8; ++nf) {
      o[nf][0] *= alr[0]; o[nf][1] *= alr[1];
      o[nf][2] *= alr[2]; o[nf][3] *= alr[3];
    }
  }
  float ps = 0.f;
  uint32_t pk0[4], pk1[4];
#pragma unroll
  for (int nf = 0; nf < 4; ++nf) {
    float p0 = __builtin_exp2f(sv[nf][0] - m);
    float p1 = __builtin_exp2f(sv[nf][1] - m);
    float p2 = __builtin_exp2f(sv[nf][2] - m);
    float p3 = __builtin_exp2f(sv[nf][3] - m);
    ps += (p0 + p1) + (p2 + p3);
    pk0[nf] = cvtpk(p0, p1);
    pk1[nf] = cvtpk(p2, p3);
  }
  ps += __shfl_xor(ps, 16);
  ps += __shfl_xor(ps, 32);
  d += ps;
#pragma unroll
  for (int ks = 0; ks < 2; ++ks) {
    uint32_t rr[4];
#pragma unroll
    for (int i = 0; i < 4; ++i) {
      uint32_t c0 = ((lg & 1) == (i >> 1)) ? pk0[2 * ks] : pk0[2 * ks + 1];
      uint32_t c1 = ((lg & 1) == (i >> 1)) ? pk1[2 * ks] : pk1[2 * ks + 1];
      uint32_t contrib = (i & 1) ? c1 : c0;
      int srclg = (lg & 1) * 2 + ((i >> 1) ^ (lg >> 1));
      rr[i] = (uint32_t)__shfl((int)contrib, lr + 16 * srclg);
    }
    u32x4 t4;
    t4[0] = (lg & 2) ? rr[2] : rr[0];
    t4[1] = (lg & 2) ? rr[3] : rr[1];
    t4[2] = (lg & 2) ? rr[0] : rr[2];
    t4[3] = (lg & 2) ? rr[1] : rr[3];
    ap[ks] = __builtin_bit_cast(short8, t4);
  }
}

__global__ __launch_bounds__(512, 4) void attn_fwd(
    const u16* __restrict__ Q, const u16* __restrict__ Kg,
    const u16* __restrict__ Vg, const float* __restrict__ biaskv,
    u16* __restrict__ AO)
{
  __shared__ u16 Ks[2][64 * 128];   // 32 KB
  __shared__ u16 Vt[2][128 * 64];   // 32 KB

  const int tid = threadIdx.x;
  const int w = tid >> 6, l = tid & 63;
  const int lr = l & 15, lg = l >> 4;
  const int sw = w >> 2;            // 0 = long stream, 1 = short stream
  const int wq = w & 3;

  const int bid = blockIdx.x;
  const int bh = bid & 31, pi = bid >> 5;   // all pi of a bh share an XCD
  const int b = bh >> 4, h = bh & 15;
  const int qtA = pi, qtB = 31 - pi;
  const int myqt = sw ? qtA : qtB;

  const size_t kvbase = ((size_t)bh) * NKV_ * HD_;
  const u16* Kh = Kg + kvbase;
  const u16* Vh = Vg + kvbase;
  const float* bkv = biaskv + b * NKV_;

  const int q0 = myqt * 64 + wq * 16;
  short8 aq[4];
  {
    const u16* qp = Q + (size_t)(b * NQ_ + q0 + lr) * D_ + h * HD_ + lg * 8;
#pragma unroll
    for (int ks = 0; ks < 4; ++ks) aq[ks] = *(const short8*)(qp + ks * 32);
  }

  f32x4 o[8] = {};
  float m = -1e30f, d = 0.f;

  short8 vv[2];
  auto stageK = [&](int buf, int kv) {
#pragma unroll
    for (int i = 0; i < 2; ++i) {
      int r = (tid >> 4) + i * 32;
      int c = (tid & 15) ^ (r & 7);
      gload_lds16(Kh + (size_t)(kv + r) * HD_ + c * 8,
                  (char*)&Ks[buf][0] + tid * 16 + i * 8192);
    }
  };
  auto loadV = [&](int kv) {
    const u16* vp = Vh + (size_t)(kv + l) * HD_ + w * 16;
#pragma unroll
    for (int j = 0; j < 2; ++j) vv[j] = *(const short8*)(vp + j * 8);
  };
  auto scatterV = [&](int buf) {
#pragma unroll
    for (int j = 0; j < 2; ++j)
#pragma unroll
      for (int e = 0; e < 8; ++e) {
        int row = w * 16 + j * 8 + e;
        Vt[buf][row * 64 + (((l >> 3) ^ (row & 7)) << 3) + (l & 7)] = (u16)vv[j][e];
      }
  };

  // prologue: tile 0 -> buf 0
  stageK(0, 0);
  loadV(0);
  scatterV(0);
  __syncthreads();

  int cur = 0;
  for (int kvt = 0; kvt <= qtB; ++kvt) {
    const int kv0 = kvt * 64;
    const bool haveNext = (kvt < qtB);
    if (haveNext) { stageK(cur ^ 1, kv0 + 64); loadV(kv0 + 64); }

    const bool active = (kvt <= myqt);
    if (active) {
      f32x4 bias4[4];
#pragma unroll
      for (int nf = 0; nf < 4; ++nf)
        bias4[nf] = *(const f32x4*)(bkv + kv0 + nf * 16 + lg * 4);

      f32x4 s[4] = {};
      __builtin_amdgcn_s_setprio(1);
#pragma unroll
      for (int nf = 0; nf < 4; ++nf) {
#pragma unroll
        for (int ks = 0; ks < 4; ++ks) {
          int row = nf * 16 + lr;
          int pch = (ks * 4 + lg) ^ (row & 7);
          short8 bk = *(const short8*)((const char*)&Ks[cur][0] + row * 256 + pch * 16);
          s[nf] = __builtin_amdgcn_mfma_f32_16x16x32_bf16(bk, aq[ks], s[nf], 0, 0, 0);
        }
      }
      __builtin_amdgcn_s_setprio(0);

      short8 ap[2];
      softmax16(s, bias4, kvt == myqt, q0 + lr, kv0, lr, lg, m, d, o, ap);

      __builtin_amdgcn_s_setprio(1);
#pragma unroll
      for (int ks = 0; ks < 2; ++ks) {
#pragma unroll
        for (int nf = 0; nf < 8; ++nf) {
          int rowv = nf * 16 + lr;
          short8 bv = *(const short8*)(&Vt[cur][0] + rowv * 64 + (((ks * 4 + lg) ^ (lr & 7)) << 3));
          o[nf] = __builtin_amdgcn_mfma_f32_16x16x32_bf16(ap[ks], bv, o[nf], 0, 0, 0);
        }
      }
      __builtin_amdgcn_s_setprio(0);
    }

    if (haveNext) scatterV(cur ^ 1);
    __syncthreads();
    cur ^= 1;
  }

  // epilogue
  float dv[4];
#pragma unroll
  for (int r = 0; r < 4; ++r) dv[r] = __shfl(d, lg * 4 + r);
#pragma unroll
  for (int r = 0; r < 4; ++r) {
    float inv = 1.f / dv[r];
    size_t row = (size_t)(b * NQ_ + q0 + lg * 4 + r);
#pragma unroll
    for (int nf = 0; nf < 8; ++nf)
      AO[row * D_ + h * HD_ + nf * 16 + lr] = f2bf(o[nf][r] * inv);
  }
}

// ---------------------------------------------------------------- launch
extern "C" void kernel_launch(void* const* d_in, const int* in_sizes, int n_in,
                              void* d_out, int out_size, void* d_ws, size_t ws_size,
                              hipStream_t stream) {
  const float* x     = (const float*)d_in[0];
  const float* k     = (const float*)d_in[1];
  const float* v     = (const float*)d_in[2];
  const int*   labels = (const int*)d_in[3];
  const unsigned char* mask = (const unsigned char*)d_in[4];
  const float* q_w   = (const float*)d_in[5];
  const float* q_b   = (const float*)d_in[6];
  const float* out_w = (const float*)d_in[7];
  const float* out_b = (const float*)d_in[8];
  const float* tbias = (const float*)d_in[9];

  char* ws = (char*)d_ws;
  u16* x_bf  = (u16*)(ws + 0);
  u16* qw_bf = (u16*)(ws + 16777216);
  u16* ow_bf = (u16*)(ws + 25165824);
  u16* k_bf  = (u16*)(ws + 33554432);
  u16* v_bf  = (u16*)(ws + 50331648);
  u16* q_bf  = (u16*)(ws + 67108864);
  u16* ao_bf = (u16*)(ws + 83886080);
  float* bkv = (float*)(ws + 100663296);

  cast_all<<<16384, 256, 0, stream>>>(x, q_w, out_w, k, v,
                                      x_bf, qw_bf, ow_bf, k_bf, v_bf);
  build_bias<<<16, 256, 0, stream>>>(labels, mask, tbias, bkv, B_ * NKV_);

  gemm256<1><<<128, 512, 0, stream>>>(x_bf, qw_bf, q_b, (void*)q_bf, QSCALE);
  attn_fwd<<<512, 512, 0, stream>>>(q_bf, k_bf, v_bf, bkv, ao_bf);
  gemm256<0><<<128, 512, 0, stream>>>(ao_bf, ow_bf, out_b, d_out, 1.0f);
}